// Round 13
// baseline (130.702 us; speedup 1.0000x reference)
//
#include <hip/hip_runtime.h>
#include <stdint.h>

// ModulatedConv2D: B=8, IC=OC=512, K=3, H=W=32
// 3 dispatches: style (sm, sm2), prep (Wtf repack + dpart demod partials +
// xsp repack), conv (implicit GEMM, 32x32x16 f16 MFMA, 8-phase schedule).
//
// R13 change: R12's 8-phase schedule gave the first real conv win (conv
// ~41us, below the harness fill). Remaining invariant: MfmaUtil ~33% in
// ALL variants -- the only never-varied property is the accumulator
// dependency structure (acc[2] -> 6-long dependent MFMA chain per phase).
// If MFMA result latency >> 32cyc issue occupancy, that chain IS the
// constant ~3x wall. Test: split accumulators by (j,kh) -> SIX independent
// floatx16 accs; each phase's 9 MFMAs = 3 independent chains of 3
// (dependent spacing 3 slots). Epilogue sums acc[j] = sum_kh. Everything
// else frozen at R12 (best total 125.6us).

#define B_   8
#define IC_  512
#define OC_  512

static constexpr float RC_DENSE = 0.04419417382415922f;   // 1/sqrt(512)
static constexpr float RC_CONV  = 0.014731391274719739f;  // 1/sqrt(4608)

typedef _Float16 half8    __attribute__((ext_vector_type(8)));
typedef float    floatx16 __attribute__((ext_vector_type(16)));

// async global->LDS, 16B per lane; LDS dest = wave-uniform base + lane*16
__device__ __forceinline__ void g2l(const void* g, void* l) {
  __builtin_amdgcn_global_load_lds(
      (const __attribute__((address_space(1))) void*)g,
      (__attribute__((address_space(3))) void*)l, 16, 0, 0);
}

// ---- sm = (w@(RC_DENSE*dw) + db + 1)*RC_CONV ; sm2 = sm^2 ----
__global__ __launch_bounds__(256) void style_kernel(
    const float* __restrict__ wv, const float* __restrict__ dw,
    const float* __restrict__ db, float* __restrict__ sm,
    float* __restrict__ sm2) {
  const int b = blockIdx.y;
  const int i = blockIdx.x * 64 + (threadIdx.x & 63);
  const int jg = threadIdx.x >> 6;
  __shared__ float red[4][64];
  float p = 0.f;
  for (int j = jg * 128; j < jg * 128 + 128; ++j)
    p += wv[b * IC_ + j] * dw[(size_t)j * IC_ + i];
  red[jg][threadIdx.x & 63] = p;
  __syncthreads();
  if (threadIdx.x < 64) {
    float s = red[0][threadIdx.x] + red[1][threadIdx.x] +
              red[2][threadIdx.x] + red[3][threadIdx.x];
    s = s * RC_DENSE + db[i] + 1.0f;
    float v = s * RC_CONV;
    sm[b * IC_ + i] = v;
    sm2[b * IC_ + i] = v * v;
  }
}

// ---------------- prep: 512 blocks (2/CU) ----------------
// bid<256 (wts role): 32oc x 32ic half-tile; Wtf[by][icb][ktq 36][oc64][8] f16
//   + dpart[icb][b][oc] = sum_icl sm2 * sum_t cw^2 (disjoint oc, no atomics)
// bid>=256 (xsp role): per (b,h) row; xsp[b][icb][r34][kk2][kq2][C34][8] f16
__global__ __launch_bounds__(256) void prep_kernel(
    const float* __restrict__ cw, const float* __restrict__ x,
    const float* __restrict__ sm, const float* __restrict__ sm2,
    _Float16* __restrict__ Wtf, float* __restrict__ dpart,
    _Float16* __restrict__ xsp) {
  __shared__ __align__(16) char smem[33280];
  const int bid = blockIdx.x;
  const int tid = threadIdx.x;
  if (bid < 256) {
    // ---------------- wts + dpart role ----------------
    _Float16* LA = (_Float16*)smem;                // 18432 B
    float* redall = (float*)(smem + 18432);        // 8192 B (8b x 8g x 32oc)
    const int by2 = bid >> 4, icb = bid & 15;
    const int by = by2 >> 1, h2 = by2 & 1;
    const int oc0 = by * 64 + h2 * 32, ic0 = icb * 32;
    const int ocl = tid & 31, g = tid >> 5;        // g 0..7
    float sq4[4] = {};
    for (int m = 0; m < 36; ++m) {
      int r = m * 8 + g;                 // r = t*32+icl; t=m>>2, icl=8*(m&3)+g
      int t = r >> 5, icl = r & 31;
      float v = cw[(size_t)(t * IC_ + ic0 + icl) * OC_ + oc0 + ocl];  // 128B seg
      sq4[m & 3] += v * v;
      LA[m * 256 + ocl * 8 + g] = (_Float16)v;     // ktq == m, j == g
    }
    for (int b = 0; b < 8; ++b) {
      float p = 0.f;
      for (int s = 0; s < 4; ++s)
        p += sm2[b * IC_ + ic0 + g + 8 * s] * sq4[s];
      redall[(b * 8 + g) * 32 + ocl] = p;
    }
    __syncthreads();
    // Wtf: 1152 contiguous-per-wave b128 chunks
    _Float16* dst = Wtf + (size_t)(by * 16 + icb) * 18432;
    for (int it = 0; it < 5; ++it) {
      int c = it * 256 + tid;
      if (c < 1152) {
        int m = c >> 5, o2 = c & 31;
        *(half8*)(dst + (size_t)(m * 64 + h2 * 32 + o2) * 8) =
            *(const half8*)&LA[m * 256 + o2 * 8];
      }
    }
    // dpart: reduce over g
    const int bb = tid >> 5, o3 = tid & 31;
    float s = 0.f;
    for (int g2 = 0; g2 < 8; ++g2) s += redall[(bb * 8 + g2) * 32 + o3];
    dpart[(size_t)icb * 4096 + bb * OC_ + oc0 + o3] = s;
  } else {
    // ---------------- xsp role ----------------
    _Float16* Xt = (_Float16*)smem;                // 32*520*2 = 33280 B
    const int rb = bid - 256;
    const int b = rb >> 5, h = rb & 31;
    for (int k = 0; k < 16; ++k) {
      int idx = k * 256 + tid;           // 512 ic * 8 w-quads
      int ic = idx >> 3, wc = (idx & 7) * 4;
      float4 v = *(const float4*)&x[((size_t)(b * IC_ + ic) * 32 + h) * 32 + wc];
      float s = sm[b * IC_ + ic];
      Xt[(wc + 0) * 520 + ic] = (_Float16)(v.x * s);
      Xt[(wc + 1) * 520 + ic] = (_Float16)(v.y * s);
      Xt[(wc + 2) * 520 + ic] = (_Float16)(v.z * s);
      Xt[(wc + 3) * 520 + ic] = (_Float16)(v.w * s);
    }
    __syncthreads();
    _Float16* xb = xsp + (size_t)b * 16 * 36992;
    const int r = h + 1;
    half8 z = {};
    for (int it = 0; it < 9; ++it) {     // 16 icb * 4 kkq * 34 C = 2176 chunks
      int c = it * 256 + tid;
      if (c < 2176) {
        int icb = c / 136, rem = c - 136 * icb, kkq = rem / 34, C = rem - 34 * kkq;
        half8 val = z;
        if (C != 0 && C != 33)
          val = *(const half8*)&Xt[(C - 1) * 520 + icb * 32 + kkq * 8];
        *(half8*)&xb[(size_t)icb * 36992 + (size_t)r * 1088 + kkq * 272 + C * 8] = val;
      }
    }
    if (h == 0 || h == 31) {             // zero top/bottom padded rows
      const int rz = (h == 0) ? 0 : 33;
      for (int it = 0; it < 9; ++it) {
        int c = it * 256 + tid;
        if (c < 2176) {
          int icb = c / 136, rem = c - 136 * icb, kkq = rem / 34, C = rem - 34 * kkq;
          *(half8*)&xb[(size_t)icb * 36992 + (size_t)rz * 1088 + kkq * 272 + C * 8] = z;
        }
      }
    }
  }
}

// ---- conv: block 64oc x 256px (8 rows), 512 thr, grid (by 8, bx 4, b 8) ----
// 256 blocks = 1/CU; XCD = linear%8 = by (weight-slice locality).
// 8 waves = wm(2 oc-halves) x wn(4 row-pairs); wave = 32oc x 2 rows.
// 16 steps x 4 phases; half-tile (kk-half: A 9216B + X 5440B) staged 3
// halves ahead; 5 g2l/wave/half (3 A + 2 X); vmcnt(10) at phases 2/4 only.
// SIX accumulators acc<j><kh> -> each phase's 9 MFMAs = 3 independent
// chains of 3 (breaks the 6-long dependent chain of the acc[2] version).

#define VM10 asm volatile("s_waitcnt vmcnt(10)" ::: "memory")
#define VM5  asm volatile("s_waitcnt vmcnt(5)" ::: "memory")
#define VM0  asm volatile("s_waitcnt vmcnt(0)" ::: "memory")
#define VMNONE ((void)0)

// one phase: ds_reads -> g2l -> bar -> lgkm0 -> 9 MFMA -> [vmcnt] -> bar
// SH=0 targets (j,kh): (0,0),(1,0),(0,1); SH=1: (1,1),(0,2),(1,2)
#define PHASE(KK, SH, PAR, DO_A, G2L_STMT, VM_STMT)                          \
  {                                                                          \
    if (DO_A) {                                                              \
      const _Float16* Ad = dyn + ((KK) * 2 + (PAR)) * 9216 +                 \
                           kq * 512 + wm * 256 + n * 8;                      \
      _Pragma("unroll")                                                      \
      for (int t_ = 0; t_ < 9; ++t_)                                         \
        av[t_] = *(const half8*)(Ad + (t_ * 2) * 512);                       \
    }                                                                        \
    const _Float16* Xd = XB + ((KK) * 2 + (PAR)) * 5440 +                    \
                         (2 * wn + 2 * (SH)) * 544 + kq * 272 + n * 8;       \
    half8 xv0[3], xv1[3];                                                    \
    _Pragma("unroll")                                                        \
    for (int kw_ = 0; kw_ < 3; ++kw_) {                                      \
      xv0[kw_] = *(const half8*)(Xd + kw_ * 8);                              \
      xv1[kw_] = *(const half8*)(Xd + 544 + kw_ * 8);                        \
    }                                                                        \
    G2L_STMT;                                                                \
    __builtin_amdgcn_s_barrier();                                            \
    asm volatile("s_waitcnt lgkmcnt(0)" ::: "memory");                       \
    __builtin_amdgcn_sched_barrier(0);                                       \
    __builtin_amdgcn_s_setprio(1);                                           \
    _Pragma("unroll")                                                        \
    for (int kw_ = 0; kw_ < 3; ++kw_) {                                      \
      if (SH == 0) {                                                         \
        acc00 = __builtin_amdgcn_mfma_f32_32x32x16_f16(av[0 + kw_], xv0[kw_], acc00, 0, 0, 0); \
        acc10 = __builtin_amdgcn_mfma_f32_32x32x16_f16(av[0 + kw_], xv1[kw_], acc10, 0, 0, 0); \
        acc01 = __builtin_amdgcn_mfma_f32_32x32x16_f16(av[3 + kw_], xv1[kw_], acc01, 0, 0, 0); \
      } else {                                                               \
        acc11 = __builtin_amdgcn_mfma_f32_32x32x16_f16(av[3 + kw_], xv0[kw_], acc11, 0, 0, 0); \
        acc02 = __builtin_amdgcn_mfma_f32_32x32x16_f16(av[6 + kw_], xv0[kw_], acc02, 0, 0, 0); \
        acc12 = __builtin_amdgcn_mfma_f32_32x32x16_f16(av[6 + kw_], xv1[kw_], acc12, 0, 0, 0); \
      }                                                                      \
    }                                                                        \
    __builtin_amdgcn_s_setprio(0);                                           \
    __builtin_amdgcn_sched_barrier(0);                                       \
    VM_STMT;                                                                 \
    __builtin_amdgcn_s_barrier();                                            \
  }

__global__ __launch_bounds__(512, 1) void conv_kernel(
    const _Float16* __restrict__ Wtf,   // [8 by][16 icb][36 m][64 oc][8]
    const _Float16* __restrict__ xsp,   // [8 b][16 icb][34 r][2 kk][2 kq][34 C][8]
    const float* __restrict__ dpart,    // [16 icb][8 b][512 oc]
    float* __restrict__ out) {          // [8][512][32][32]
  extern __shared__ __align__(16) _Float16 dyn[];
  _Float16* XB = dyn + 36864;           // X regions base (halfs)
  float* redd = (float*)(dyn + 58624);  // 8*64 floats
  float* dvl  = redd + 512;             // 64 floats

  const int by = blockIdx.x, bx = blockIdx.y, b = blockIdx.z;
  const int tid = threadIdx.x, lane = tid & 63, w = tid >> 6;  // w 0..7
  const int wm = w & 1, wn = w >> 1;    // wm: oc half; wn: row pair
  const int n = lane & 31, kq = lane >> 5;
  const int h0 = bx * 8;                // out rows h0..h0+7; padded h0..h0+9

  const _Float16* gA = Wtf + (size_t)(by * 16) * 18432;
  const _Float16* gX = xsp + (size_t)b * 16 * 36992 + (size_t)h0 * 1088;

  // A-half(kk) of icb: 18 m-values (m = (mi>>1)*4 + kk*2 + (mi&1)),
  // 1152 chunks; wave w covers c in [w*144, w*144+144): 2 full + 1@16.
  auto stageA3 = [&](int g) {
    const int icb = g >> 1, kk = g & 1, par = icb & 1;
    const _Float16* a = gA + (size_t)icb * 18432;
    _Float16* Ad = dyn + (kk * 2 + par) * 9216;
#pragma unroll
    for (int k = 0; k < 2; ++k) {
      int c = w * 144 + k * 64 + lane;
      int mi = c >> 6, o = c & 63;
      int m = (mi >> 1) * 4 + kk * 2 + (mi & 1);
      g2l(a + (size_t)(m * 512 + o * 8), Ad + c * 8);
    }
    {
      int c = w * 144 + 128 + lane;
      if (lane < 16) {
        int mi = c >> 6, o = c & 63;
        int m = (mi >> 1) * 4 + kk * 2 + (mi & 1);
        g2l(a + (size_t)(m * 512 + o * 8), Ad + c * 8);
      }
    }
  };
  // X-half(kk) of icb: 10 rows x 544 halfs = 680 chunks; wave w covers
  // c in [w*85, w*85+85): 1 full + 1@21.
  auto stageX2 = [&](int g) {
    const int icb = g >> 1, kk = g & 1, par = icb & 1;
    const _Float16* xg = gX + (size_t)icb * 36992 + kk * 544;
    _Float16* Xd = XB + (kk * 2 + par) * 5440;
    {
      int c = w * 85 + lane;
      int r = c / 68, o = c - r * 68;
      g2l(xg + (size_t)(r * 1088 + o * 8), Xd + c * 8);
    }
    {
      int c = w * 85 + 64 + lane;
      if (lane < 21) {
        int r = c / 68, o = c - r * 68;
        g2l(xg + (size_t)(r * 1088 + o * 8), Xd + c * 8);
      }
    }
  };

  floatx16 acc00 = {}, acc01 = {}, acc02 = {};
  floatx16 acc10 = {}, acc11 = {}, acc12 = {};
  half8 av[9];
  // prologue: stage halves 0,1,2 (15 g2l/wave); drain half0; barrier.
  stageA3(0); stageX2(0);
  stageA3(1); stageX2(1);
  stageA3(2); stageX2(2);
  VM10;                                  // <=10 left: halves 1,2
  __builtin_amdgcn_s_barrier();

  for (int st = 0; st < 14; ++st) {
    const int par = st & 1;
    const int g3 = 2 * st + 3, g4 = 2 * st + 4;
    PHASE(0, 0, par, true,  stageA3(g3), VMNONE)
    PHASE(0, 1, par, false, stageX2(g3), VM10)   // drains half 2st+1 for P3
    PHASE(1, 0, par, true,  stageA3(g4), VMNONE)
    PHASE(1, 1, par, false, stageX2(g4), VM10)   // drains half 2st+2 for next P1
  }
  // st = 14 (par 0): stage half 31 only
  PHASE(0, 0, 0, true,  stageA3(31), VMNONE)
  PHASE(0, 1, 0, false, stageX2(31), VM10)       // drains half 29
  PHASE(1, 0, 0, true,  VMNONE, VMNONE)
  PHASE(1, 1, 0, false, VMNONE, VM5)             // drains half 30
  // st = 15 (par 1): no staging
  PHASE(0, 0, 1, true,  VMNONE, VMNONE)
  PHASE(0, 1, 1, false, VMNONE, VM0)             // drains half 31
  PHASE(1, 0, 1, true,  VMNONE, VMNONE)
  PHASE(1, 1, 1, false, VMNONE, VMNONE)

  // fold the six accumulators
  floatx16 accf0 = acc00 + acc01 + acc02;
  floatx16 accf1 = acc10 + acc11 + acc12;

  // epilogue: reduce dpart over 16 icb -> dvl[64], then plain stores
  const int oc0 = by * 64 + wm * 32;
  __syncthreads();
  {
    const int oc_l = tid & 63, ig = tid >> 6;   // 8 groups x 64 oc
    float s = dpart[(size_t)(ig * 2) * 4096 + b * OC_ + by * 64 + oc_l] +
              dpart[(size_t)(ig * 2 + 1) * 4096 + b * OC_ + by * 64 + oc_l];
    redd[ig * 64 + oc_l] = s;
  }
  __syncthreads();
  if (tid < 64) {
    float s = 1e-8f;
#pragma unroll
    for (int g = 0; g < 8; ++g) s += redd[g * 64 + tid];
    dvl[tid] = rsqrtf(s);
  }
  __syncthreads();
  // D col(px)=n, row(oc within 32)=(rg&3)+8*(rg>>2)+4*kq
  const int r0 = h0 + 2 * wn;
#pragma unroll
  for (int rg = 0; rg < 16; ++rg) {
    const int row = (rg & 3) + 8 * (rg >> 2) + 4 * kq;
    const float dv = dvl[wm * 32 + row];
    float* op = out + ((size_t)b * OC_ + oc0 + row) * 1024 + r0 * 32 + n;
    op[0]  = accf0[rg] * dv;
    op[32] = accf1[rg] * dv;
  }
}

extern "C" void kernel_launch(void* const* d_in, const int* in_sizes, int n_in,
                              void* d_out, int out_size, void* d_ws, size_t ws_size,
                              hipStream_t stream) {
  const float* x       = (const float*)d_in[0];
  const float* w       = (const float*)d_in[1];
  const float* conv_w  = (const float*)d_in[2];
  const float* dense_w = (const float*)d_in[3];
  const float* dense_b = (const float*)d_in[4];
  float* out = (float*)d_out;

  char* ws = (char*)d_ws;
  float*    sm    = (float*)ws;                        // 16 KB
  float*    sm2   = (float*)(ws + (16 << 10));         // 16 KB
  float*    dpart = (float*)(ws + (32 << 10));         // 256 KB
  _Float16* Wtf   = (_Float16*)(ws + (288 << 10));               // 4,718,592 B
  _Float16* xsp   = (_Float16*)(ws + (288 << 10) + 4718592);     // 9,469,952 B

  static int dyn_set = 0;
  if (!dyn_set) {
    hipFuncSetAttribute((const void*)conv_kernel,
                        hipFuncAttributeMaxDynamicSharedMemorySize, 119552);
    dyn_set = 1;
  }

  style_kernel<<<dim3(8, B_), 256, 0, stream>>>(w, dense_w, dense_b, sm, sm2);
  prep_kernel<<<512, 256, 0, stream>>>(conv_w, x, sm, sm2, Wtf, dpart, xsp);
  conv_kernel<<<dim3(8, 4, B_), 512, 119552, stream>>>(Wtf, xsp, dpart, out);
}

// Round 14
// 128.924 us; speedup vs baseline: 1.0138x; 1.0138x over previous
//
#include <hip/hip_runtime.h>
#include <stdint.h>

// ModulatedConv2D: B=8, IC=OC=512, K=3, H=W=32
// 3 dispatches: style (sm, sm2), prep (wts role 256 blocks + xsp role
// 1024 quarter-blocks, fused), conv (implicit GEMM, 8-phase schedule).
//
// R14 change: R13's acc-split regressed (130.7 vs R12's 125.6) -> conv
// reverted to R12 exactly. New lever: prep (est. 25-30us vs ~5us memory
// floor; never measured) -- latency-bound at 2 blocks/CU with long serial
// chains. Fix: fuse R7's PROVEN 4x-parallel xsp decomposition (per
// (b,h,ic-quarter), identical index math) into the SINGLE prep dispatch:
// grid 1280, LDS 33280->26624 B -> 6 blocks/CU, 4x shorter chains.

#define B_   8
#define IC_  512
#define OC_  512

static constexpr float RC_DENSE = 0.04419417382415922f;   // 1/sqrt(512)
static constexpr float RC_CONV  = 0.014731391274719739f;  // 1/sqrt(4608)

typedef _Float16 half8    __attribute__((ext_vector_type(8)));
typedef float    floatx16 __attribute__((ext_vector_type(16)));

// async global->LDS, 16B per lane; LDS dest = wave-uniform base + lane*16
__device__ __forceinline__ void g2l(const void* g, void* l) {
  __builtin_amdgcn_global_load_lds(
      (const __attribute__((address_space(1))) void*)g,
      (__attribute__((address_space(3))) void*)l, 16, 0, 0);
}

// ---- sm = (w@(RC_DENSE*dw) + db + 1)*RC_CONV ; sm2 = sm^2 ----
__global__ __launch_bounds__(256) void style_kernel(
    const float* __restrict__ wv, const float* __restrict__ dw,
    const float* __restrict__ db, float* __restrict__ sm,
    float* __restrict__ sm2) {
  const int b = blockIdx.y;
  const int i = blockIdx.x * 64 + (threadIdx.x & 63);
  const int jg = threadIdx.x >> 6;
  __shared__ float red[4][64];
  float p = 0.f;
  for (int j = jg * 128; j < jg * 128 + 128; ++j)
    p += wv[b * IC_ + j] * dw[(size_t)j * IC_ + i];
  red[jg][threadIdx.x & 63] = p;
  __syncthreads();
  if (threadIdx.x < 64) {
    float s = red[0][threadIdx.x] + red[1][threadIdx.x] +
              red[2][threadIdx.x] + red[3][threadIdx.x];
    s = s * RC_DENSE + db[i] + 1.0f;
    float v = s * RC_CONV;
    sm[b * IC_ + i] = v;
    sm2[b * IC_ + i] = v * v;
  }
}

// ---------------- prep: 1280 blocks (6/CU by LDS) ----------------
// bid<256 (wts role): 32oc x 32ic half-tile; Wtf[by][icb][m 36][oc64][8] f16
//   + dpart[icb][b][oc] = sum_icl sm2 * sum_t cw^2 (disjoint oc, no atomics)
// bid>=256 (xsp role, 1024 blocks): per (b,h,q ic-quarter);
//   xsp[b][icb][r34][kk2][kq2][C34][8] f16 with halo cols + 0-rows.
__global__ __launch_bounds__(256) void prep_kernel(
    const float* __restrict__ cw, const float* __restrict__ x,
    const float* __restrict__ sm, const float* __restrict__ sm2,
    _Float16* __restrict__ Wtf, float* __restrict__ dpart,
    _Float16* __restrict__ xsp) {
  __shared__ __align__(16) char smem[26624];
  const int bid = blockIdx.x;
  const int tid = threadIdx.x;
  if (bid < 256) {
    // ---------------- wts + dpart role ----------------
    _Float16* LA = (_Float16*)smem;                // 18432 B
    float* redall = (float*)(smem + 18432);        // 8192 B (8b x 8g x 32oc)
    const int by2 = bid >> 4, icb = bid & 15;
    const int by = by2 >> 1, h2 = by2 & 1;
    const int oc0 = by * 64 + h2 * 32, ic0 = icb * 32;
    const int ocl = tid & 31, g = tid >> 5;        // g 0..7
    float sq4[4] = {};
    for (int m = 0; m < 36; ++m) {
      int r = m * 8 + g;                 // r = t*32+icl; t=m>>2, icl=8*(m&3)+g
      int t = r >> 5, icl = r & 31;
      float v = cw[(size_t)(t * IC_ + ic0 + icl) * OC_ + oc0 + ocl];  // 128B seg
      sq4[m & 3] += v * v;
      LA[m * 256 + ocl * 8 + g] = (_Float16)v;     // ktq == m, j == g
    }
    for (int b = 0; b < 8; ++b) {
      float p = 0.f;
      for (int s = 0; s < 4; ++s)
        p += sm2[b * IC_ + ic0 + g + 8 * s] * sq4[s];
      redall[(b * 8 + g) * 32 + ocl] = p;
    }
    __syncthreads();
    // Wtf: 1152 contiguous-per-wave b128 chunks
    _Float16* dst = Wtf + (size_t)(by * 16 + icb) * 18432;
    for (int it = 0; it < 5; ++it) {
      int c = it * 256 + tid;
      if (c < 1152) {
        int m = c >> 5, o2 = c & 31;
        *(half8*)(dst + (size_t)(m * 64 + h2 * 32 + o2) * 8) =
            *(const half8*)&LA[m * 256 + o2 * 8];
      }
    }
    // dpart: reduce over g
    const int bb = tid >> 5, o3 = tid & 31;
    float s = 0.f;
    for (int g2 = 0; g2 < 8; ++g2) s += redall[(bb * 8 + g2) * 32 + o3];
    dpart[(size_t)icb * 4096 + bb * OC_ + oc0 + o3] = s;
  } else {
    // ---------------- xsp role: per (b, h, ic-quarter) ----------------
    _Float16* Xt = (_Float16*)smem;                // [32 w][136 icl], 8704 B
    const int rb = bid - 256;                      // 0..1023
    const int q = rb >> 8;                         // ic quarter 0..3
    const int b = (rb >> 5) & 7, h = rb & 31;
    const int ic0 = q * 128;
    for (int k = 0; k < 4; ++k) {
      int idx = k * 256 + tid;           // 128 ic * 8 w-quads
      int icl = idx >> 3, wc = (idx & 7) * 4;
      float4 v = *(const float4*)&x[((size_t)(b * IC_ + ic0 + icl) * 32 + h) * 32 + wc];
      float s = sm[b * IC_ + ic0 + icl];
      Xt[(wc + 0) * 136 + icl] = (_Float16)(v.x * s);
      Xt[(wc + 1) * 136 + icl] = (_Float16)(v.y * s);
      Xt[(wc + 2) * 136 + icl] = (_Float16)(v.z * s);
      Xt[(wc + 3) * 136 + icl] = (_Float16)(v.w * s);
    }
    __syncthreads();
    _Float16* xb = xsp + (size_t)b * 16 * 36992;
    const int r = h + 1;
    half8 z = {};
    for (int it = 0; it < 3; ++it) {     // 4 icb * 4 kkq * 34 C = 544 chunks
      int c = it * 256 + tid;
      if (c < 544) {
        int icbl = c / 136, rem = c - 136 * icbl, kkq = rem / 34, C = rem - 34 * kkq;
        half8 val = z;
        if (C != 0 && C != 33)
          val = *(const half8*)&Xt[(C - 1) * 136 + icbl * 32 + kkq * 8];
        int icb = q * 4 + icbl;
        *(half8*)&xb[(size_t)icb * 36992 + (size_t)r * 1088 + kkq * 272 + C * 8] = val;
      }
    }
    if (h == 0 || h == 31) {             // zero top/bottom padded rows
      const int rz = (h == 0) ? 0 : 33;
      for (int it = 0; it < 3; ++it) {
        int c = it * 256 + tid;
        if (c < 544) {
          int icbl = c / 136, rem = c - 136 * icbl, kkq = rem / 34, C = rem - 34 * kkq;
          int icb = q * 4 + icbl;
          *(half8*)&xb[(size_t)icb * 36992 + (size_t)rz * 1088 + kkq * 272 + C * 8] = z;
        }
      }
    }
  }
}

// ---- conv: block 64oc x 256px (8 rows), 512 thr, grid (by 8, bx 4, b 8) ----
// 256 blocks = 1/CU; XCD = linear%8 = by (weight-slice locality).
// 8 waves = wm(2 oc-halves) x wn(4 row-pairs); wave = 32oc x 2 rows,
// acc[2]x16, 36 MFMA per step, 16 steps (full icb each).
// 8-phase schedule (R12, best): 4 phases per step; half-tile (kk-half:
// A 9216B + X 5440B) staged 3 halves ahead; 5 g2l/wave/half (3 A + 2 X).
// vmcnt(10) at phases 2/4 only (never 0 in main loop).

#define VM10 asm volatile("s_waitcnt vmcnt(10)" ::: "memory")
#define VM5  asm volatile("s_waitcnt vmcnt(5)" ::: "memory")
#define VM0  asm volatile("s_waitcnt vmcnt(0)" ::: "memory")
#define VMNONE ((void)0)

// one phase: ds_reads -> g2l -> bar -> lgkm0 -> 9 MFMA -> [vmcnt] -> bar
#define PHASE(KK, SH, PAR, DO_A, G2L_STMT, VM_STMT)                          \
  {                                                                          \
    if (DO_A) {                                                              \
      const _Float16* Ad = dyn + ((KK) * 2 + (PAR)) * 9216 +                 \
                           kq * 512 + wm * 256 + n * 8;                      \
      _Pragma("unroll")                                                      \
      for (int t_ = 0; t_ < 9; ++t_)                                         \
        av[t_] = *(const half8*)(Ad + (t_ * 2) * 512);                       \
    }                                                                        \
    const _Float16* Xd = XB + ((KK) * 2 + (PAR)) * 5440 +                    \
                         (2 * wn + 2 * (SH)) * 544 + kq * 272 + n * 8;       \
    half8 xv0[3], xv1[3];                                                    \
    _Pragma("unroll")                                                        \
    for (int kw_ = 0; kw_ < 3; ++kw_) {                                      \
      xv0[kw_] = *(const half8*)(Xd + kw_ * 8);                              \
      xv1[kw_] = *(const half8*)(Xd + 544 + kw_ * 8);                        \
    }                                                                        \
    G2L_STMT;                                                                \
    __builtin_amdgcn_s_barrier();                                            \
    asm volatile("s_waitcnt lgkmcnt(0)" ::: "memory");                       \
    __builtin_amdgcn_sched_barrier(0);                                       \
    __builtin_amdgcn_s_setprio(1);                                           \
    _Pragma("unroll")                                                        \
    for (int kw_ = 0; kw_ < 3; ++kw_) {                                      \
      if (SH == 0) {                                                         \
        acc[0] = __builtin_amdgcn_mfma_f32_32x32x16_f16(av[0 + kw_], xv0[kw_], acc[0], 0, 0, 0); \
        acc[1] = __builtin_amdgcn_mfma_f32_32x32x16_f16(av[0 + kw_], xv1[kw_], acc[1], 0, 0, 0); \
        acc[0] = __builtin_amdgcn_mfma_f32_32x32x16_f16(av[3 + kw_], xv1[kw_], acc[0], 0, 0, 0); \
      } else {                                                               \
        acc[1] = __builtin_amdgcn_mfma_f32_32x32x16_f16(av[3 + kw_], xv0[kw_], acc[1], 0, 0, 0); \
        acc[0] = __builtin_amdgcn_mfma_f32_32x32x16_f16(av[6 + kw_], xv0[kw_], acc[0], 0, 0, 0); \
        acc[1] = __builtin_amdgcn_mfma_f32_32x32x16_f16(av[6 + kw_], xv1[kw_], acc[1], 0, 0, 0); \
      }                                                                      \
    }                                                                        \
    __builtin_amdgcn_s_setprio(0);                                           \
    __builtin_amdgcn_sched_barrier(0);                                       \
    VM_STMT;                                                                 \
    __builtin_amdgcn_s_barrier();                                            \
  }

__global__ __launch_bounds__(512, 1) void conv_kernel(
    const _Float16* __restrict__ Wtf,   // [8 by][16 icb][36 m][64 oc][8]
    const _Float16* __restrict__ xsp,   // [8 b][16 icb][34 r][2 kk][2 kq][34 C][8]
    const float* __restrict__ dpart,    // [16 icb][8 b][512 oc]
    float* __restrict__ out) {          // [8][512][32][32]
  extern __shared__ __align__(16) _Float16 dyn[];
  _Float16* XB = dyn + 36864;           // X regions base (halfs)
  float* redd = (float*)(dyn + 58624);  // 8*64 floats
  float* dvl  = redd + 512;             // 64 floats

  const int by = blockIdx.x, bx = blockIdx.y, b = blockIdx.z;
  const int tid = threadIdx.x, lane = tid & 63, w = tid >> 6;  // w 0..7
  const int wm = w & 1, wn = w >> 1;    // wm: oc half; wn: row pair
  const int n = lane & 31, kq = lane >> 5;
  const int h0 = bx * 8;                // out rows h0..h0+7; padded h0..h0+9

  const _Float16* gA = Wtf + (size_t)(by * 16) * 18432;
  const _Float16* gX = xsp + (size_t)b * 16 * 36992 + (size_t)h0 * 1088;

  // A-half(kk) of icb: 18 m-values (m = (mi>>1)*4 + kk*2 + (mi&1)),
  // 1152 chunks; wave w covers c in [w*144, w*144+144): 2 full + 1@16.
  auto stageA3 = [&](int g) {
    const int icb = g >> 1, kk = g & 1, par = icb & 1;
    const _Float16* a = gA + (size_t)icb * 18432;
    _Float16* Ad = dyn + (kk * 2 + par) * 9216;
#pragma unroll
    for (int k = 0; k < 2; ++k) {
      int c = w * 144 + k * 64 + lane;
      int mi = c >> 6, o = c & 63;
      int m = (mi >> 1) * 4 + kk * 2 + (mi & 1);
      g2l(a + (size_t)(m * 512 + o * 8), Ad + c * 8);
    }
    {
      int c = w * 144 + 128 + lane;
      if (lane < 16) {
        int mi = c >> 6, o = c & 63;
        int m = (mi >> 1) * 4 + kk * 2 + (mi & 1);
        g2l(a + (size_t)(m * 512 + o * 8), Ad + c * 8);
      }
    }
  };
  // X-half(kk) of icb: 10 rows x 544 halfs = 680 chunks; wave w covers
  // c in [w*85, w*85+85): 1 full + 1@21.
  auto stageX2 = [&](int g) {
    const int icb = g >> 1, kk = g & 1, par = icb & 1;
    const _Float16* xg = gX + (size_t)icb * 36992 + kk * 544;
    _Float16* Xd = XB + (kk * 2 + par) * 5440;
    {
      int c = w * 85 + lane;
      int r = c / 68, o = c - r * 68;
      g2l(xg + (size_t)(r * 1088 + o * 8), Xd + c * 8);
    }
    {
      int c = w * 85 + 64 + lane;
      if (lane < 21) {
        int r = c / 68, o = c - r * 68;
        g2l(xg + (size_t)(r * 1088 + o * 8), Xd + c * 8);
      }
    }
  };

  floatx16 acc[2] = {};
  half8 av[9];
  // prologue: stage halves 0,1,2 (15 g2l/wave); drain half0; barrier.
  stageA3(0); stageX2(0);
  stageA3(1); stageX2(1);
  stageA3(2); stageX2(2);
  VM10;                                  // <=10 left: halves 1,2
  __builtin_amdgcn_s_barrier();

  for (int st = 0; st < 14; ++st) {
    const int par = st & 1;
    const int g3 = 2 * st + 3, g4 = 2 * st + 4;
    PHASE(0, 0, par, true,  stageA3(g3), VMNONE)
    PHASE(0, 1, par, false, stageX2(g3), VM10)   // drains half 2st+1 for P3
    PHASE(1, 0, par, true,  stageA3(g4), VMNONE)
    PHASE(1, 1, par, false, stageX2(g4), VM10)   // drains half 2st+2 for next P1
  }
  // st = 14 (par 0): stage half 31 only
  PHASE(0, 0, 0, true,  stageA3(31), VMNONE)
  PHASE(0, 1, 0, false, stageX2(31), VM10)       // drains half 29
  PHASE(1, 0, 0, true,  VMNONE, VMNONE)
  PHASE(1, 1, 0, false, VMNONE, VM5)             // drains half 30
  // st = 15 (par 1): no staging
  PHASE(0, 0, 1, true,  VMNONE, VMNONE)
  PHASE(0, 1, 1, false, VMNONE, VM0)             // drains half 31
  PHASE(1, 0, 1, true,  VMNONE, VMNONE)
  PHASE(1, 1, 1, false, VMNONE, VMNONE)

  // epilogue: reduce dpart over 16 icb -> dvl[64], then plain stores
  const int oc0 = by * 64 + wm * 32;
  __syncthreads();
  {
    const int oc_l = tid & 63, ig = tid >> 6;   // 8 groups x 64 oc
    float s = dpart[(size_t)(ig * 2) * 4096 + b * OC_ + by * 64 + oc_l] +
              dpart[(size_t)(ig * 2 + 1) * 4096 + b * OC_ + by * 64 + oc_l];
    redd[ig * 64 + oc_l] = s;
  }
  __syncthreads();
  if (tid < 64) {
    float s = 1e-8f;
#pragma unroll
    for (int g = 0; g < 8; ++g) s += redd[g * 64 + tid];
    dvl[tid] = rsqrtf(s);
  }
  __syncthreads();
  // D col(px)=n, row(oc within 32)=(rg&3)+8*(rg>>2)+4*kq
  const int r0 = h0 + 2 * wn;
#pragma unroll
  for (int rg = 0; rg < 16; ++rg) {
    const int row = (rg & 3) + 8 * (rg >> 2) + 4 * kq;
    const float dv = dvl[wm * 32 + row];
    float* op = out + ((size_t)b * OC_ + oc0 + row) * 1024 + r0 * 32 + n;
    op[0]  = acc[0][rg] * dv;
    op[32] = acc[1][rg] * dv;
  }
}

extern "C" void kernel_launch(void* const* d_in, const int* in_sizes, int n_in,
                              void* d_out, int out_size, void* d_ws, size_t ws_size,
                              hipStream_t stream) {
  const float* x       = (const float*)d_in[0];
  const float* w       = (const float*)d_in[1];
  const float* conv_w  = (const float*)d_in[2];
  const float* dense_w = (const float*)d_in[3];
  const float* dense_b = (const float*)d_in[4];
  float* out = (float*)d_out;

  char* ws = (char*)d_ws;
  float*    sm    = (float*)ws;                        // 16 KB
  float*    sm2   = (float*)(ws + (16 << 10));         // 16 KB
  float*    dpart = (float*)(ws + (32 << 10));         // 256 KB
  _Float16* Wtf   = (_Float16*)(ws + (288 << 10));               // 4,718,592 B
  _Float16* xsp   = (_Float16*)(ws + (288 << 10) + 4718592);     // 9,469,952 B

  static int dyn_set = 0;
  if (!dyn_set) {
    hipFuncSetAttribute((const void*)conv_kernel,
                        hipFuncAttributeMaxDynamicSharedMemorySize, 119552);
    dyn_set = 1;
  }

  style_kernel<<<dim3(8, B_), 256, 0, stream>>>(w, dense_w, dense_b, sm, sm2);
  prep_kernel<<<1280, 256, 0, stream>>>(conv_w, x, sm, sm2, Wtf, dpart, xsp);
  conv_kernel<<<dim3(8, 4, B_), 512, 119552, stream>>>(Wtf, xsp, dpart, out);
}

// Round 15
// 127.134 us; speedup vs baseline: 1.0281x; 1.0141x over previous
//
#include <hip/hip_runtime.h>
#include <stdint.h>

// ModulatedConv2D: B=8, IC=OC=512, K=3, H=W=32
// 3 dispatches: style (sm, sm2), prep (R12 fused 512-block), conv
// (implicit GEMM, 8-phase schedule + REGISTER-PIPELINED ds_reads).
//
// R15 change: prep reverted to R12 (R14's 4x split was +3us). Conv model
// that fits all 14 rounds: barriers put 8 waves in lockstep, so each
// phase SERIALIZES [ds_read window ~670cyc] + [MFMA window ~576cyc/SIMD]
// -> 1556cyc observed, MfmaUtil = 576/1556 = 37%. Fix: issue each phase's
// fragment reads ONE PHASE EARLY into alternate register sets (xvA/xvB,
// avA/avB); guard MFMA with COUNTED lgkmcnt(6/15) = only the reads just
// issued remain; vmcnt drains moved to P1/P3 (8) so regions are valid one
// phase before their reads. Reads overlap prior MFMA window.

#define B_   8
#define IC_  512
#define OC_  512

static constexpr float RC_DENSE = 0.04419417382415922f;   // 1/sqrt(512)
static constexpr float RC_CONV  = 0.014731391274719739f;  // 1/sqrt(4608)

typedef _Float16 half8    __attribute__((ext_vector_type(8)));
typedef float    floatx16 __attribute__((ext_vector_type(16)));

// async global->LDS, 16B per lane; LDS dest = wave-uniform base + lane*16
__device__ __forceinline__ void g2l(const void* g, void* l) {
  __builtin_amdgcn_global_load_lds(
      (const __attribute__((address_space(1))) void*)g,
      (__attribute__((address_space(3))) void*)l, 16, 0, 0);
}

// ---- sm = (w@(RC_DENSE*dw) + db + 1)*RC_CONV ; sm2 = sm^2 ----
__global__ __launch_bounds__(256) void style_kernel(
    const float* __restrict__ wv, const float* __restrict__ dw,
    const float* __restrict__ db, float* __restrict__ sm,
    float* __restrict__ sm2) {
  const int b = blockIdx.y;
  const int i = blockIdx.x * 64 + (threadIdx.x & 63);
  const int jg = threadIdx.x >> 6;
  __shared__ float red[4][64];
  float p = 0.f;
  for (int j = jg * 128; j < jg * 128 + 128; ++j)
    p += wv[b * IC_ + j] * dw[(size_t)j * IC_ + i];
  red[jg][threadIdx.x & 63] = p;
  __syncthreads();
  if (threadIdx.x < 64) {
    float s = red[0][threadIdx.x] + red[1][threadIdx.x] +
              red[2][threadIdx.x] + red[3][threadIdx.x];
    s = s * RC_DENSE + db[i] + 1.0f;
    float v = s * RC_CONV;
    sm[b * IC_ + i] = v;
    sm2[b * IC_ + i] = v * v;
  }
}

// ---------------- prep: 512 blocks (2/CU) — R12 fused version ----------------
__global__ __launch_bounds__(256) void prep_kernel(
    const float* __restrict__ cw, const float* __restrict__ x,
    const float* __restrict__ sm, const float* __restrict__ sm2,
    _Float16* __restrict__ Wtf, float* __restrict__ dpart,
    _Float16* __restrict__ xsp) {
  __shared__ __align__(16) char smem[33280];
  const int bid = blockIdx.x;
  const int tid = threadIdx.x;
  if (bid < 256) {
    // ---------------- wts + dpart role ----------------
    _Float16* LA = (_Float16*)smem;                // 18432 B
    float* redall = (float*)(smem + 18432);        // 8192 B (8b x 8g x 32oc)
    const int by2 = bid >> 4, icb = bid & 15;
    const int by = by2 >> 1, h2 = by2 & 1;
    const int oc0 = by * 64 + h2 * 32, ic0 = icb * 32;
    const int ocl = tid & 31, g = tid >> 5;        // g 0..7
    float sq4[4] = {};
    for (int m = 0; m < 36; ++m) {
      int r = m * 8 + g;                 // r = t*32+icl; t=m>>2, icl=8*(m&3)+g
      int t = r >> 5, icl = r & 31;
      float v = cw[(size_t)(t * IC_ + ic0 + icl) * OC_ + oc0 + ocl];  // 128B seg
      sq4[m & 3] += v * v;
      LA[m * 256 + ocl * 8 + g] = (_Float16)v;     // ktq == m, j == g
    }
    for (int b = 0; b < 8; ++b) {
      float p = 0.f;
      for (int s = 0; s < 4; ++s)
        p += sm2[b * IC_ + ic0 + g + 8 * s] * sq4[s];
      redall[(b * 8 + g) * 32 + ocl] = p;
    }
    __syncthreads();
    // Wtf: 1152 contiguous-per-wave b128 chunks
    _Float16* dst = Wtf + (size_t)(by * 16 + icb) * 18432;
    for (int it = 0; it < 5; ++it) {
      int c = it * 256 + tid;
      if (c < 1152) {
        int m = c >> 5, o2 = c & 31;
        *(half8*)(dst + (size_t)(m * 64 + h2 * 32 + o2) * 8) =
            *(const half8*)&LA[m * 256 + o2 * 8];
      }
    }
    // dpart: reduce over g
    const int bb = tid >> 5, o3 = tid & 31;
    float s = 0.f;
    for (int g2 = 0; g2 < 8; ++g2) s += redall[(bb * 8 + g2) * 32 + o3];
    dpart[(size_t)icb * 4096 + bb * OC_ + oc0 + o3] = s;
  } else {
    // ---------------- xsp role ----------------
    _Float16* Xt = (_Float16*)smem;                // 32*520*2 = 33280 B
    const int rb = bid - 256;
    const int b = rb >> 5, h = rb & 31;
    for (int k = 0; k < 16; ++k) {
      int idx = k * 256 + tid;           // 512 ic * 8 w-quads
      int ic = idx >> 3, wc = (idx & 7) * 4;
      float4 v = *(const float4*)&x[((size_t)(b * IC_ + ic) * 32 + h) * 32 + wc];
      float s = sm[b * IC_ + ic];
      Xt[(wc + 0) * 520 + ic] = (_Float16)(v.x * s);
      Xt[(wc + 1) * 520 + ic] = (_Float16)(v.y * s);
      Xt[(wc + 2) * 520 + ic] = (_Float16)(v.z * s);
      Xt[(wc + 3) * 520 + ic] = (_Float16)(v.w * s);
    }
    __syncthreads();
    _Float16* xb = xsp + (size_t)b * 16 * 36992;
    const int r = h + 1;
    half8 z = {};
    for (int it = 0; it < 9; ++it) {     // 16 icb * 4 kkq * 34 C = 2176 chunks
      int c = it * 256 + tid;
      if (c < 2176) {
        int icb = c / 136, rem = c - 136 * icb, kkq = rem / 34, C = rem - 34 * kkq;
        half8 val = z;
        if (C != 0 && C != 33)
          val = *(const half8*)&Xt[(C - 1) * 520 + icb * 32 + kkq * 8];
        *(half8*)&xb[(size_t)icb * 36992 + (size_t)r * 1088 + kkq * 272 + C * 8] = val;
      }
    }
    if (h == 0 || h == 31) {             // zero top/bottom padded rows
      const int rz = (h == 0) ? 0 : 33;
      for (int it = 0; it < 9; ++it) {
        int c = it * 256 + tid;
        if (c < 2176) {
          int icb = c / 136, rem = c - 136 * icb, kkq = rem / 34, C = rem - 34 * kkq;
          *(half8*)&xb[(size_t)icb * 36992 + (size_t)rz * 1088 + kkq * 272 + C * 8] = z;
        }
      }
    }
  }
}

// ---- conv: block 64oc x 256px (8 rows), 512 thr, grid (by 8, bx 4, b 8) ----
// 256 blocks = 1/CU; XCD = linear%8 = by. 8 waves = wm(2) x wn(4);
// wave = 32oc x 2 rows, acc[2]x16, 36 MFMA/step, 16 steps x 4 phases.
// Register-pipelined reads: phase p issues p+1's fragment reads into the
// alternate set; MFMA guarded by counted lgkmcnt (only p+1's reads newer).
// vmcnt(8) at P1/P3 ends: region valid one phase before its reads.

#define VM10 asm volatile("s_waitcnt vmcnt(10)" ::: "memory")
#define VM8  asm volatile("s_waitcnt vmcnt(8)"  ::: "memory")
#define VM5  asm volatile("s_waitcnt vmcnt(5)"  ::: "memory")
#define VM0  asm volatile("s_waitcnt vmcnt(0)"  ::: "memory")
#define LG15 asm volatile("s_waitcnt lgkmcnt(15)" ::: "memory")
#define LG6  asm volatile("s_waitcnt lgkmcnt(6)"  ::: "memory")
#define LG0  asm volatile("s_waitcnt lgkmcnt(0)"  ::: "memory")
#define VMNONE ((void)0)

// issue 6 X-fragment reads for a phase (KK,SH,PAR) into set XV{0,1}
#define LOADX(XV, KK, SH, PAR)                                               \
  {                                                                          \
    const _Float16* Xd_ = XB + ((KK) * 2 + (PAR)) * 5440 +                   \
                          (2 * wn + 2 * (SH)) * 544 + kq * 272 + n * 8;      \
    _Pragma("unroll")                                                        \
    for (int kw_ = 0; kw_ < 3; ++kw_) {                                      \
      XV##0[kw_] = *(const half8*)(Xd_ + kw_ * 8);                           \
      XV##1[kw_] = *(const half8*)(Xd_ + 544 + kw_ * 8);                     \
    }                                                                        \
  }
// issue 9 A-fragment reads for (KK,PAR) into set AV
#define LOADA(AV, KK, PAR)                                                   \
  {                                                                          \
    const _Float16* Ad_ = dyn + ((KK) * 2 + (PAR)) * 9216 +                  \
                          kq * 512 + wm * 256 + n * 8;                       \
    _Pragma("unroll")                                                        \
    for (int t_ = 0; t_ < 9; ++t_)                                           \
      AV[t_] = *(const half8*)(Ad_ + (t_ * 2) * 512);                        \
  }

#define MFMA9(AV, XV, SH)                                                    \
    _Pragma("unroll")                                                        \
    for (int kw_ = 0; kw_ < 3; ++kw_) {                                      \
      if (SH == 0) {                                                         \
        acc[0] = __builtin_amdgcn_mfma_f32_32x32x16_f16(AV[0 + kw_], XV##0[kw_], acc[0], 0, 0, 0); \
        acc[1] = __builtin_amdgcn_mfma_f32_32x32x16_f16(AV[0 + kw_], XV##1[kw_], acc[1], 0, 0, 0); \
        acc[0] = __builtin_amdgcn_mfma_f32_32x32x16_f16(AV[3 + kw_], XV##1[kw_], acc[0], 0, 0, 0); \
      } else {                                                               \
        acc[1] = __builtin_amdgcn_mfma_f32_32x32x16_f16(AV[3 + kw_], XV##0[kw_], acc[1], 0, 0, 0); \
        acc[0] = __builtin_amdgcn_mfma_f32_32x32x16_f16(AV[6 + kw_], XV##0[kw_], acc[0], 0, 0, 0); \
        acc[1] = __builtin_amdgcn_mfma_f32_32x32x16_f16(AV[6 + kw_], XV##1[kw_], acc[1], 0, 0, 0); \
      }                                                                      \
    }

// phase: [issue next-phase reads] [g2l] bar [counted lgkm] MFMA [vm] bar
#define PHASE(AV, XV, SH, LOADS_STMT, G2L_STMT, LG_STMT, VM_STMT)            \
  {                                                                          \
    __builtin_amdgcn_sched_barrier(0);                                       \
    LOADS_STMT;                                                              \
    __builtin_amdgcn_sched_barrier(0);                                       \
    G2L_STMT;                                                                \
    __builtin_amdgcn_s_barrier();                                            \
    LG_STMT;                                                                 \
    __builtin_amdgcn_sched_barrier(0);                                       \
    __builtin_amdgcn_s_setprio(1);                                           \
    MFMA9(AV, XV, SH)                                                        \
    __builtin_amdgcn_s_setprio(0);                                           \
    __builtin_amdgcn_sched_barrier(0);                                       \
    VM_STMT;                                                                 \
    __builtin_amdgcn_s_barrier();                                            \
  }

__global__ __launch_bounds__(512, 1) void conv_kernel(
    const _Float16* __restrict__ Wtf,   // [8 by][16 icb][36 m][64 oc][8]
    const _Float16* __restrict__ xsp,   // [8 b][16 icb][34 r][2 kk][2 kq][34 C][8]
    const float* __restrict__ dpart,    // [16 icb][8 b][512 oc]
    float* __restrict__ out) {          // [8][512][32][32]
  extern __shared__ __align__(16) _Float16 dyn[];
  _Float16* XB = dyn + 36864;           // X regions base (halfs)
  float* redd = (float*)(dyn + 58624);  // 8*64 floats
  float* dvl  = redd + 512;             // 64 floats

  const int by = blockIdx.x, bx = blockIdx.y, b = blockIdx.z;
  const int tid = threadIdx.x, lane = tid & 63, w = tid >> 6;  // w 0..7
  const int wm = w & 1, wn = w >> 1;    // wm: oc half; wn: row pair
  const int n = lane & 31, kq = lane >> 5;
  const int h0 = bx * 8;                // out rows h0..h0+7; padded h0..h0+9

  const _Float16* gA = Wtf + (size_t)(by * 16) * 18432;
  const _Float16* gX = xsp + (size_t)b * 16 * 36992 + (size_t)h0 * 1088;

  // A-half(kk) of icb: 1152 chunks; wave w: 2 full + 1@16 g2l (3/wave)
  auto stageA3 = [&](int g) {
    const int icb = g >> 1, kk = g & 1, par = icb & 1;
    const _Float16* a = gA + (size_t)icb * 18432;
    _Float16* Ad = dyn + (kk * 2 + par) * 9216;
#pragma unroll
    for (int k = 0; k < 2; ++k) {
      int c = w * 144 + k * 64 + lane;
      int mi = c >> 6, o = c & 63;
      int m = (mi >> 1) * 4 + kk * 2 + (mi & 1);
      g2l(a + (size_t)(m * 512 + o * 8), Ad + c * 8);
    }
    {
      int c = w * 144 + 128 + lane;
      if (lane < 16) {
        int mi = c >> 6, o = c & 63;
        int m = (mi >> 1) * 4 + kk * 2 + (mi & 1);
        g2l(a + (size_t)(m * 512 + o * 8), Ad + c * 8);
      }
    }
  };
  // X-half(kk) of icb: 680 chunks; wave w: 1 full + 1@21 g2l (2/wave)
  auto stageX2 = [&](int g) {
    const int icb = g >> 1, kk = g & 1, par = icb & 1;
    const _Float16* xg = gX + (size_t)icb * 36992 + kk * 544;
    _Float16* Xd = XB + (kk * 2 + par) * 5440;
    {
      int c = w * 85 + lane;
      int r = c / 68, o = c - r * 68;
      g2l(xg + (size_t)(r * 1088 + o * 8), Xd + c * 8);
    }
    {
      int c = w * 85 + 64 + lane;
      if (lane < 21) {
        int r = c / 68, o = c - r * 68;
        g2l(xg + (size_t)(r * 1088 + o * 8), Xd + c * 8);
      }
    }
  };

  floatx16 acc[2] = {};
  half8 avA[9], avB[9];
  half8 xvA0[3], xvA1[3], xvB0[3], xvB1[3];

  // prologue: stage halves 0,1,2 (15 g2l/wave); drain half0; barrier;
  // then issue step0-P1's reads (avA kk0 par0 + xvA SH0) = 15 ds ops.
  stageA3(0); stageX2(0);
  stageA3(1); stageX2(1);
  stageA3(2); stageX2(2);
  VM10;                                  // <=10 left: halves 1,2 in flight
  __builtin_amdgcn_s_barrier();
  LOADA(avA, 0, 0)
  LOADX(xvA, 0, 0, 0)
  __builtin_amdgcn_sched_barrier(0);

  for (int st = 0; st < 14; ++st) {
    const int par = st & 1, nxt = par ^ 1;
    const int g3 = 2 * st + 3, g4 = 2 * st + 4;
    // P1: consume (avA,xvA,SH0); load xvB for P2; stage A(g3); VM8 drains
    //     half 2st+1 (kk1,par) -> valid for P2's loads.
    PHASE(avA, xvA, 0, LOADX(xvB, 0, 1, par), stageA3(g3), LG6, VM8)
    // P2: consume (avA,xvB,SH1); load avB+xvA for P3 (kk1,par); stage X(g3).
    PHASE(avA, xvB, 1, LOADA(avB, 1, par); LOADX(xvA, 1, 0, par),
          stageX2(g3), LG15, VMNONE)
    // P3: consume (avB,xvA,SH0); load xvB for P4; stage A(g4); VM8 drains
    //     half 2st+2 (kk0,nxt) -> valid for P4's loads.
    PHASE(avB, xvA, 0, LOADX(xvB, 1, 1, par), stageA3(g4), LG6, VM8)
    // P4: consume (avB,xvB,SH1); load avA+xvA for next P1 (kk0,nxt); X(g4).
    PHASE(avB, xvB, 1, LOADA(avA, 0, nxt); LOADX(xvA, 0, 0, nxt),
          stageX2(g4), LG15, VMNONE)
  }
  // step 14 (par 0): stage only half 31
  PHASE(avA, xvA, 0, LOADX(xvB, 0, 1, 0), stageA3(31), LG6, VM8)   // drains 29
  PHASE(avA, xvB, 1, LOADA(avB, 1, 0); LOADX(xvA, 1, 0, 0), stageX2(31), LG15, VMNONE)
  PHASE(avB, xvA, 0, LOADX(xvB, 1, 1, 0), VMNONE, LG6, VM5)        // drains 30
  PHASE(avB, xvB, 1, LOADA(avA, 0, 1); LOADX(xvA, 0, 0, 1), VMNONE, LG15, VMNONE)
  // step 15 (par 1): no staging
  PHASE(avA, xvA, 0, LOADX(xvB, 0, 1, 1), VMNONE, LG6, VM0)        // drains 31
  PHASE(avA, xvB, 1, LOADA(avB, 1, 1); LOADX(xvA, 1, 0, 1), VMNONE, LG15, VMNONE)
  PHASE(avB, xvA, 0, LOADX(xvB, 1, 1, 1), VMNONE, LG6, VMNONE)
  PHASE(avB, xvB, 1, VMNONE, VMNONE, LG0, VMNONE)

  // epilogue: reduce dpart over 16 icb -> dvl[64], then plain stores
  const int oc0 = by * 64 + wm * 32;
  __syncthreads();
  {
    const int oc_l = tid & 63, ig = tid >> 6;   // 8 groups x 64 oc
    float s = dpart[(size_t)(ig * 2) * 4096 + b * OC_ + by * 64 + oc_l] +
              dpart[(size_t)(ig * 2 + 1) * 4096 + b * OC_ + by * 64 + oc_l];
    redd[ig * 64 + oc_l] = s;
  }
  __syncthreads();
  if (tid < 64) {
    float s = 1e-8f;
#pragma unroll
    for (int g = 0; g < 8; ++g) s += redd[g * 64 + tid];
    dvl[tid] = rsqrtf(s);
  }
  __syncthreads();
  // D col(px)=n, row(oc within 32)=(rg&3)+8*(rg>>2)+4*kq
  const int r0 = h0 + 2 * wn;
#pragma unroll
  for (int rg = 0; rg < 16; ++rg) {
    const int row = (rg & 3) + 8 * (rg >> 2) + 4 * kq;
    const float dv = dvl[wm * 32 + row];
    float* op = out + ((size_t)b * OC_ + oc0 + row) * 1024 + r0 * 32 + n;
    op[0]  = acc[0][rg] * dv;
    op[32] = acc[1][rg] * dv;
  }
}

extern "C" void kernel_launch(void* const* d_in, const int* in_sizes, int n_in,
                              void* d_out, int out_size, void* d_ws, size_t ws_size,
                              hipStream_t stream) {
  const float* x       = (const float*)d_in[0];
  const float* w       = (const float*)d_in[1];
  const float* conv_w  = (const float*)d_in[2];
  const float* dense_w = (const float*)d_in[3];
  const float* dense_b = (const float*)d_in[4];
  float* out = (float*)d_out;

  char* ws = (char*)d_ws;
  float*    sm    = (float*)ws;                        // 16 KB
  float*    sm2   = (float*)(ws + (16 << 10));         // 16 KB
  float*    dpart = (float*)(ws + (32 << 10));         // 256 KB
  _Float16* Wtf   = (_Float16*)(ws + (288 << 10));               // 4,718,592 B
  _Float16* xsp   = (_Float16*)(ws + (288 << 10) + 4718592);     // 9,469,952 B

  static int dyn_set = 0;
  if (!dyn_set) {
    hipFuncSetAttribute((const void*)conv_kernel,
                        hipFuncAttributeMaxDynamicSharedMemorySize, 119552);
    dyn_set = 1;
  }

  style_kernel<<<dim3(8, B_), 256, 0, stream>>>(w, dense_w, dense_b, sm, sm2);
  prep_kernel<<<512, 256, 0, stream>>>(conv_w, x, sm, sm2, Wtf, dpart, xsp);
  conv_kernel<<<dim3(8, 4, B_), 512, 119552, stream>>>(Wtf, xsp, dpart, out);
}